// Round 1
// 14160.455 us; speedup vs baseline: 1.5274x; 1.5274x over previous
//
#include <hip/hip_runtime.h>

// Problem constants
#define TSTEPS 300
// d_out float-element offsets: [outs 300*64*2 | r_m1 | r_pmd | r_s1]
#define OFF_RM1  38400
#define RSTRIDE  9830400    // 300*64*512 per rate region
#define NBLK 97             // 96 compute blocks + 1 out-writer

// ws float layout:
//   [0        .. 98303 ] x-state [3][64][512]
//   [98304    .. 131071] partial r_s1 @ W_s1_pmd  [64][512]
//   [131072   .. ]       int area: 32 colblock flags + 1 grid-barrier counter
#define WS_PARTIAL 98304
#define WS_FLAGS   131072
#define WS_TOTAL   131200

typedef float f4 __attribute__((ext_vector_type(4)));

// ---------------------------------------------------------------------------
// init: zero x-state, partial, flags, outs[0], rates[0] (tanh(0)=0).
// ---------------------------------------------------------------------------
__global__ __launch_bounds__(256) void rnn_init(float* ws, float* dout) {
  int gid = blockIdx.x * blockDim.x + threadIdx.x;
  int stride = gridDim.x * blockDim.x;
  for (int i = gid; i < WS_TOTAL; i += stride) ws[i] = 0.f;
  for (int i = gid; i < 128; i += stride) dout[i] = 0.f;
  for (int i = gid; i < 3 * 32768; i += stride) {
    int rr = i >> 15, j = i & 32767;
    dout[OFF_RM1 + (size_t)rr * RSTRIDE + j] = 0.f;
  }
}

// ---------------------------------------------------------------------------
// grid barrier: monotonic counter, target = t*NBLK. Cooperative launch
// guarantees co-residency. tid0 release-publishes block writes (device
// scope -> L2 writeback) and acquire-invalidates before re-reading rates.
// ---------------------------------------------------------------------------
__device__ __forceinline__ void gridbar(int* ctr, int target) {
  __syncthreads();
  if (threadIdx.x == 0) {
    __threadfence();
    __hip_atomic_fetch_add(ctr, 1, __ATOMIC_RELEASE, __HIP_MEMORY_SCOPE_AGENT);
    while (__hip_atomic_load(ctr, __ATOMIC_ACQUIRE, __HIP_MEMORY_SCOPE_AGENT) < target)
      __builtin_amdgcn_s_sleep(2);
  }
  __syncthreads();
}

// ---------------------------------------------------------------------------
// persistent kernel: 97 blocks x 256 threads, cooperative.
// blk 0..31: m1   (16 cols each)  segs: LDS=W_pmd_m1,          GLB=W_rec_m1
// blk 32..63: pmd (16 cols each)  segs: LDS=W_m1_pmd+W_out@W_fb, GLB=W_rec_pmd
//                                  + s1-partial via ws flag
// blk 64..95: s1  (16 cols each)  segs: LDS=W_s1_pmd (partial->pmd),
//                                        GLB=W_rec_s1 (+ stim @ W_in_s1)
// blk 96: lagged out-writer (outs[t-1]) + outs[299] tail.
// One grid barrier per step; weights staged to LDS once.
// ---------------------------------------------------------------------------
__global__ __launch_bounds__(256) void rnn_persist(
    const float* __restrict__ stim,
    const float* __restrict__ W_rec_m1, const float* __restrict__ W_rec_pmd,
    const float* __restrict__ W_rec_s1,
    const float* __restrict__ W_pmd_m1, const float* __restrict__ b_pmd_m1,
    const float* __restrict__ W_m1_pmd, const float* __restrict__ b_m1_pmd,
    const float* __restrict__ W_s1_pmd, const float* __restrict__ b_s1_pmd,
    const float* __restrict__ W_in_s1,  const float* __restrict__ b_in_s1,
    const float* __restrict__ W_out_m1, const float* __restrict__ b_out_m1,
    const float* __restrict__ W_fb_pmd, const float* __restrict__ b_fb_pmd,
    float* __restrict__ ws, float* __restrict__ dout)
{
  __shared__ float Wl[8192];    // [k][16] col slice of the LDS segment
  __shared__ float Winp[160];   // s1 only: W_in_s1 [10][16] slice

  const int blk = blockIdx.x;
  const int tid = threadIdx.x;
  int* flags  = (int*)(ws + WS_FLAGS);   // [32] per-colblock s1->pmd flags
  int* barctr = flags + 32;              // grid barrier counter
  float* partial = ws + WS_PARTIAL;      // [64][512]

  // ---------------- out-writer block ----------------
  if (blk == 96) {
    for (int t = 1; t < TSTEPS; ++t) {
      if (t >= 2 && tid < 64) {
        const float* rm = dout + OFF_RM1 + (size_t)(t - 1) * 32768 + tid * 512;
        float o0 = 0.f, o1 = 0.f;
        #pragma unroll 4
        for (int k0 = 0; k0 < 512; k0 += 4) {
          f4 r  = *(const f4*)(rm + k0);
          f4 wa = *(const f4*)(W_out_m1 + k0 * 2);
          f4 wb = *(const f4*)(W_out_m1 + k0 * 2 + 4);
          o0 += r.x * wa.x + r.y * wa.z + r.z * wb.x + r.w * wb.z;
          o1 += r.x * wa.y + r.y * wa.w + r.z * wb.y + r.w * wb.w;
        }
        dout[(t - 1) * 128 + tid * 2]     = o0 + b_out_m1[0];
        dout[(t - 1) * 128 + tid * 2 + 1] = o1 + b_out_m1[1];
      }
      gridbar(barctr, t * NBLK);
    }
    if (tid < 64) {  // outs[299]
      const float* rm = dout + OFF_RM1 + (size_t)(TSTEPS - 1) * 32768 + tid * 512;
      float o0 = 0.f, o1 = 0.f;
      #pragma unroll 4
      for (int k0 = 0; k0 < 512; k0 += 4) {
        f4 r  = *(const f4*)(rm + k0);
        f4 wa = *(const f4*)(W_out_m1 + k0 * 2);
        f4 wb = *(const f4*)(W_out_m1 + k0 * 2 + 4);
        o0 += r.x * wa.x + r.y * wa.z + r.z * wb.x + r.w * wb.z;
        o1 += r.x * wa.y + r.y * wa.w + r.z * wb.y + r.w * wb.w;
      }
      dout[(TSTEPS - 1) * 128 + tid * 2]     = o0 + b_out_m1[0];
      dout[(TSTEPS - 1) * 128 + tid * 2 + 1] = o1 + b_out_m1[1];
    }
    return;
  }

  // ---------------- compute blocks ----------------
  const int region = blk >> 5;          // 0=m1, 1=pmd, 2=s1
  const int c = blk & 31;               // colblock
  const int n0 = c << 4;
  const int nq = tid & 3;
  const int bb = tid >> 2;
  const int n  = n0 + nq * 4;

  // ---- stage LDS segment (once) ----
  if (region == 0) {
    for (int idx = tid; idx < 8192; idx += 256) {
      int k = idx >> 4, cc = idx & 15;
      Wl[idx] = W_pmd_m1[(size_t)k * 512 + n0 + cc];
    }
  } else if (region == 1) {
    // fold feedback: W_eff = W_m1_pmd + W_out @ W_fb (rank-2)
    for (int idx = tid; idx < 8192; idx += 256) {
      int k = idx >> 4, cc = idx & 15;
      int col = n0 + cc;
      Wl[idx] = W_m1_pmd[(size_t)k * 512 + col]
              + W_out_m1[k * 2]     * W_fb_pmd[col]
              + W_out_m1[k * 2 + 1] * W_fb_pmd[512 + col];
    }
  } else {
    for (int idx = tid; idx < 8192; idx += 256) {
      int k = idx >> 4, cc = idx & 15;
      Wl[idx] = W_s1_pmd[(size_t)k * 512 + n0 + cc];
    }
    for (int idx = tid; idx < 160; idx += 256) {
      int k = idx >> 4, cc = idx & 15;
      Winp[idx] = W_in_s1[(size_t)k * 512 + n0 + cc];
    }
  }

  // biases / global-seg pointer in registers
  f4 bias;
  f4 beff2 = {0.f, 0.f, 0.f, 0.f};
  const float* Wg;
  if (region == 0) {
    bias = *(const f4*)(b_pmd_m1 + n);
    Wg = W_rec_m1;
  } else if (region == 1) {
    bias  = *(const f4*)(b_m1_pmd + n);
    bias += *(const f4*)(b_s1_pmd + n);
    bias += *(const f4*)(b_fb_pmd + n);
    beff2 = b_out_m1[0] * *(const f4*)(W_fb_pmd + n)
          + b_out_m1[1] * *(const f4*)(W_fb_pmd + 512 + n);
    Wg = W_rec_pmd;
  } else {
    bias = *(const f4*)(b_in_s1 + n);
    Wg = W_rec_s1;
  }
  __syncthreads();

  float* xp   = ws + region * 32768 + bb * 512 + n;   // thread-owned x
  float* prow = partial + bb * 512 + n;

  for (int t = 1; t < TSTEPS; ++t) {
    const float* rm1p  = dout + OFF_RM1 + (size_t)(t - 1) * 32768;
    const float* rpmdp = rm1p + RSTRIDE;
    const float* rs1p  = rpmdp + RSTRIDE;
    f4 pre;

    if (region == 2) {
      // --- s1: phase 1: partial for pmd (LDS seg), publish early ---
      const float* ra = rs1p + bb * 512;
      f4 accP = {0.f, 0.f, 0.f, 0.f};
      #pragma unroll 2
      for (int k0 = 0; k0 < 512; k0 += 4) {
        f4 r = *(const f4*)(ra + k0);
        const float* wl = &Wl[k0 * 16 + nq * 4];
        f4 a0 = *(const f4*)(wl);
        f4 a1 = *(const f4*)(wl + 16);
        f4 a2 = *(const f4*)(wl + 32);
        f4 a3 = *(const f4*)(wl + 48);
        accP += r.x * a0; accP += r.y * a1; accP += r.z * a2; accP += r.w * a3;
      }
      __builtin_nontemporal_store(accP, (f4*)prow);
      __syncthreads();
      if (tid == 0) {
        __threadfence();
        __hip_atomic_fetch_add(&flags[c], 1, __ATOMIC_RELEASE, __HIP_MEMORY_SCOPE_AGENT);
      }
      // --- phase 2: own recurrence (global seg) + input ---
      f4 accX = {0.f, 0.f, 0.f, 0.f};
      const float* wg = Wg + n;
      #pragma unroll 2
      for (int k0 = 0; k0 < 512; k0 += 4) {
        f4 r  = *(const f4*)(ra + k0);
        f4 g0 = *(const f4*)(wg);
        f4 g1 = *(const f4*)(wg + 512);
        f4 g2 = *(const f4*)(wg + 1024);
        f4 g3 = *(const f4*)(wg + 1536);
        wg += 2048;
        accX += r.x * g0; accX += r.y * g1; accX += r.z * g2; accX += r.w * g3;
      }
      const float* u = stim + (size_t)t * 640 + bb * 10;
      f4 accI = bias;
      #pragma unroll
      for (int j = 0; j < 10; ++j)
        accI += u[j] * *(const f4*)(&Winp[j * 16 + nq * 4]);
      pre = accX + accI;
    } else {
      // --- m1 / pmd: fused dual-segment loop (LDS pipe + VMEM pipe) ---
      const float* ra = (region == 0 ? rpmdp : rm1p)  + bb * 512;  // LDS-seg src
      const float* rb = (region == 0 ? rm1p  : rpmdp) + bb * 512;  // GLB-seg src
      f4 accA = {0.f, 0.f, 0.f, 0.f};
      f4 accB = {0.f, 0.f, 0.f, 0.f};
      const float* wg = Wg + n;
      #pragma unroll 2
      for (int k0 = 0; k0 < 512; k0 += 4) {
        f4 r1 = *(const f4*)(ra + k0);
        f4 r2 = *(const f4*)(rb + k0);
        const float* wl = &Wl[k0 * 16 + nq * 4];
        f4 a0 = *(const f4*)(wl);
        f4 a1 = *(const f4*)(wl + 16);
        f4 a2 = *(const f4*)(wl + 32);
        f4 a3 = *(const f4*)(wl + 48);
        f4 g0 = *(const f4*)(wg);
        f4 g1 = *(const f4*)(wg + 512);
        f4 g2 = *(const f4*)(wg + 1024);
        f4 g3 = *(const f4*)(wg + 1536);
        wg += 2048;
        accA += r1.x * a0; accA += r1.y * a1; accA += r1.z * a2; accA += r1.w * a3;
        accB += r2.x * g0; accB += r2.y * g1; accB += r2.z * g2; accB += r2.w * g3;
      }
      if (region == 0) {
        pre = accA + accB + bias;
      } else {
        // wait for s1's partial for this step (s1 publishes at ~half our loop)
        while (__hip_atomic_load(&flags[c], __ATOMIC_ACQUIRE, __HIP_MEMORY_SCOPE_AGENT) < t)
          __builtin_amdgcn_s_sleep(1);
        pre = accA + accB + bias + *(const f4*)prow;
        if (t >= 2) pre += beff2;
      }
    }

    // ---- leaky update + tanh; x thread-owned; rate published nontemporal ----
    f4 xv = *(const f4*)xp;
    xv = 0.8f * xv + 0.2f * pre;
    *(f4*)xp = xv;
    f4 rv = {tanhf(xv.x), tanhf(xv.y), tanhf(xv.z), tanhf(xv.w)};
    float* rh = dout + OFF_RM1 + (size_t)region * RSTRIDE
              + (size_t)t * 32768 + bb * 512 + n;
    __builtin_nontemporal_store(rv, (f4*)rh);

    gridbar(barctr, t * NBLK);
  }
}

extern "C" void kernel_launch(void* const* d_in, const int* in_sizes, int n_in,
                              void* d_out, int out_size, void* d_ws, size_t ws_size,
                              hipStream_t stream) {
  const float* stim      = (const float*)d_in[0];
  const float* W_rec_m1  = (const float*)d_in[1];
  const float* W_rec_pmd = (const float*)d_in[2];
  const float* W_rec_s1  = (const float*)d_in[3];
  const float* W_pmd_m1  = (const float*)d_in[4];
  const float* b_pmd_m1  = (const float*)d_in[5];
  const float* W_m1_pmd  = (const float*)d_in[6];
  const float* b_m1_pmd  = (const float*)d_in[7];
  const float* W_s1_pmd  = (const float*)d_in[8];
  const float* b_s1_pmd  = (const float*)d_in[9];
  const float* W_in_s1   = (const float*)d_in[10];
  const float* b_in_s1   = (const float*)d_in[11];
  const float* W_out_m1  = (const float*)d_in[12];
  const float* b_out_m1  = (const float*)d_in[13];
  const float* W_fb_pmd  = (const float*)d_in[14];
  const float* b_fb_pmd  = (const float*)d_in[15];

  float* ws   = (float*)d_ws;
  float* dout = (float*)d_out;

  hipLaunchKernelGGL(rnn_init, dim3(512), dim3(256), 0, stream, ws, dout);

  void* args[] = {
    (void*)&stim,
    (void*)&W_rec_m1, (void*)&W_rec_pmd, (void*)&W_rec_s1,
    (void*)&W_pmd_m1, (void*)&b_pmd_m1,
    (void*)&W_m1_pmd, (void*)&b_m1_pmd,
    (void*)&W_s1_pmd, (void*)&b_s1_pmd,
    (void*)&W_in_s1,  (void*)&b_in_s1,
    (void*)&W_out_m1, (void*)&b_out_m1,
    (void*)&W_fb_pmd, (void*)&b_fb_pmd,
    (void*)&ws, (void*)&dout
  };
  hipLaunchCooperativeKernel((const void*)rnn_persist, dim3(NBLK), dim3(256),
                             args, 0, stream);
}

// Round 2
// 10535.963 us; speedup vs baseline: 2.0529x; 1.3440x over previous
//
#include <hip/hip_runtime.h>

// Problem constants
#define TSTEPS 300
// d_out float-element offsets: [outs 300*64*2 | r_m1 | r_pmd | r_s1]
#define OFF_RM1  38400
#define RSTRIDE  9830400    // 300*64*512 per rate region
#define NBLK 97             // 96 compute blocks + 1 out-writer

// ws float layout:
//   [0        .. 98303 ] x-state [3][64][512]
//   [98304    .. 131071] partial r_s1 @ W_s1_pmd  [64][512]
//   [131072   .. ]       int area: 32 colblock flags + 1 grid-barrier counter
#define WS_PARTIAL 98304
#define WS_FLAGS   131072
#define WS_TOTAL   131200

typedef float f4 __attribute__((ext_vector_type(4)));

// ---------------------------------------------------------------------------
// coherent publish/fetch: relaxed agent-scope atomics (sc1 per-access
// write-through / coherence-point read). No fences -> no buffer_wbl2/inv.
// ---------------------------------------------------------------------------
__device__ __forceinline__ void publish4(float* p, f4 v) {
  __hip_atomic_store(p + 0, v.x, __ATOMIC_RELAXED, __HIP_MEMORY_SCOPE_AGENT);
  __hip_atomic_store(p + 1, v.y, __ATOMIC_RELAXED, __HIP_MEMORY_SCOPE_AGENT);
  __hip_atomic_store(p + 2, v.z, __ATOMIC_RELAXED, __HIP_MEMORY_SCOPE_AGENT);
  __hip_atomic_store(p + 3, v.w, __ATOMIC_RELAXED, __HIP_MEMORY_SCOPE_AGENT);
}
__device__ __forceinline__ f4 fetch4(const float* p) {
  f4 v;
  v.x = __hip_atomic_load(p + 0, __ATOMIC_RELAXED, __HIP_MEMORY_SCOPE_AGENT);
  v.y = __hip_atomic_load(p + 1, __ATOMIC_RELAXED, __HIP_MEMORY_SCOPE_AGENT);
  v.z = __hip_atomic_load(p + 2, __ATOMIC_RELAXED, __HIP_MEMORY_SCOPE_AGENT);
  v.w = __hip_atomic_load(p + 3, __ATOMIC_RELAXED, __HIP_MEMORY_SCOPE_AGENT);
  return v;
}

// ---------------------------------------------------------------------------
// init: zero x-state, partial, flags, outs[0], rates[0] (tanh(0)=0).
// ---------------------------------------------------------------------------
__global__ __launch_bounds__(256) void rnn_init(float* ws, float* dout) {
  int gid = blockIdx.x * blockDim.x + threadIdx.x;
  int stride = gridDim.x * blockDim.x;
  for (int i = gid; i < WS_TOTAL; i += stride) ws[i] = 0.f;
  for (int i = gid; i < 128; i += stride) dout[i] = 0.f;
  for (int i = gid; i < 3 * 32768; i += stride) {
    int rr = i >> 15, j = i & 32767;
    dout[OFF_RM1 + (size_t)rr * RSTRIDE + j] = 0.f;
  }
}

// ---------------------------------------------------------------------------
// grid barrier: monotonic counter, target = t*NBLK. All cross-block data was
// already pushed to the coherence point by sc1 stores + vmcnt(0), so the
// barrier itself needs NO release/acquire fences (no wbl2, no inv).
// __syncthreads() emits s_waitcnt vmcnt(0) before s_barrier, guaranteeing
// every wave's stores are acked before tid0 signals arrival.
// ---------------------------------------------------------------------------
__device__ __forceinline__ void gridbar(int* ctr, int target) {
  __syncthreads();
  if (threadIdx.x == 0) {
    __hip_atomic_fetch_add(ctr, 1, __ATOMIC_RELAXED, __HIP_MEMORY_SCOPE_AGENT);
    while (__hip_atomic_load(ctr, __ATOMIC_RELAXED, __HIP_MEMORY_SCOPE_AGENT) < target)
      __builtin_amdgcn_s_sleep(2);
  }
  asm volatile("" ::: "memory");
  __syncthreads();
}

// ---------------------------------------------------------------------------
// persistent kernel: 97 blocks x 256 threads, cooperative.
// blk 0..31: m1   (16 cols each)  segs: LDS=W_pmd_m1,            GLB=W_rec_m1
// blk 32..63: pmd (16 cols each)  segs: LDS=W_m1_pmd+W_out@W_fb, GLB=W_rec_pmd
//                                  + s1-partial via ws flag
// blk 64..95: s1  (16 cols each)  segs: LDS=W_s1_pmd (partial->pmd),
//                                        GLB=W_rec_s1 (+ stim @ W_in_s1)
// blk 96: lagged out-writer (outs[t-1]) + outs[299] tail.
// ---------------------------------------------------------------------------
__global__ __launch_bounds__(256) void rnn_persist(
    const float* __restrict__ stim,
    const float* __restrict__ W_rec_m1, const float* __restrict__ W_rec_pmd,
    const float* __restrict__ W_rec_s1,
    const float* __restrict__ W_pmd_m1, const float* __restrict__ b_pmd_m1,
    const float* __restrict__ W_m1_pmd, const float* __restrict__ b_m1_pmd,
    const float* __restrict__ W_s1_pmd, const float* __restrict__ b_s1_pmd,
    const float* __restrict__ W_in_s1,  const float* __restrict__ b_in_s1,
    const float* __restrict__ W_out_m1, const float* __restrict__ b_out_m1,
    const float* __restrict__ W_fb_pmd, const float* __restrict__ b_fb_pmd,
    float* __restrict__ ws, float* __restrict__ dout)
{
  __shared__ float Wl[8192];    // [k][16] col slice of the LDS segment
  __shared__ float Winp[160];   // s1 only: W_in_s1 [10][16] slice

  const int blk = blockIdx.x;
  const int tid = threadIdx.x;
  int* flags  = (int*)(ws + WS_FLAGS);   // [32] per-colblock s1->pmd flags
  int* barctr = flags + 32;              // grid barrier counter
  float* partial = ws + WS_PARTIAL;      // [64][512]

  // ---------------- out-writer block ----------------
  if (blk == 96) {
    for (int t = 1; t < TSTEPS; ++t) {
      if (t >= 2 && tid < 64) {
        const float* rm = dout + OFF_RM1 + (size_t)(t - 1) * 32768 + tid * 512;
        float o0 = 0.f, o1 = 0.f;
        #pragma unroll 4
        for (int k0 = 0; k0 < 512; k0 += 4) {
          f4 r  = *(const f4*)(rm + k0);
          f4 wa = *(const f4*)(W_out_m1 + k0 * 2);
          f4 wb = *(const f4*)(W_out_m1 + k0 * 2 + 4);
          o0 += r.x * wa.x + r.y * wa.z + r.z * wb.x + r.w * wb.z;
          o1 += r.x * wa.y + r.y * wa.w + r.z * wb.y + r.w * wb.w;
        }
        dout[(t - 1) * 128 + tid * 2]     = o0 + b_out_m1[0];
        dout[(t - 1) * 128 + tid * 2 + 1] = o1 + b_out_m1[1];
      }
      gridbar(barctr, t * NBLK);
    }
    if (tid < 64) {  // outs[299]
      const float* rm = dout + OFF_RM1 + (size_t)(TSTEPS - 1) * 32768 + tid * 512;
      float o0 = 0.f, o1 = 0.f;
      #pragma unroll 4
      for (int k0 = 0; k0 < 512; k0 += 4) {
        f4 r  = *(const f4*)(rm + k0);
        f4 wa = *(const f4*)(W_out_m1 + k0 * 2);
        f4 wb = *(const f4*)(W_out_m1 + k0 * 2 + 4);
        o0 += r.x * wa.x + r.y * wa.z + r.z * wb.x + r.w * wb.z;
        o1 += r.x * wa.y + r.y * wa.w + r.z * wb.y + r.w * wb.w;
      }
      dout[(TSTEPS - 1) * 128 + tid * 2]     = o0 + b_out_m1[0];
      dout[(TSTEPS - 1) * 128 + tid * 2 + 1] = o1 + b_out_m1[1];
    }
    return;
  }

  // ---------------- compute blocks ----------------
  const int region = blk >> 5;          // 0=m1, 1=pmd, 2=s1
  const int c = blk & 31;               // colblock
  const int n0 = c << 4;
  const int nq = tid & 3;
  const int bb = tid >> 2;
  const int n  = n0 + nq * 4;

  // ---- stage LDS segment (once) ----
  if (region == 0) {
    for (int idx = tid; idx < 8192; idx += 256) {
      int k = idx >> 4, cc = idx & 15;
      Wl[idx] = W_pmd_m1[(size_t)k * 512 + n0 + cc];
    }
  } else if (region == 1) {
    // fold feedback: W_eff = W_m1_pmd + W_out @ W_fb (rank-2)
    for (int idx = tid; idx < 8192; idx += 256) {
      int k = idx >> 4, cc = idx & 15;
      int col = n0 + cc;
      Wl[idx] = W_m1_pmd[(size_t)k * 512 + col]
              + W_out_m1[k * 2]     * W_fb_pmd[col]
              + W_out_m1[k * 2 + 1] * W_fb_pmd[512 + col];
    }
  } else {
    for (int idx = tid; idx < 8192; idx += 256) {
      int k = idx >> 4, cc = idx & 15;
      Wl[idx] = W_s1_pmd[(size_t)k * 512 + n0 + cc];
    }
    for (int idx = tid; idx < 160; idx += 256) {
      int k = idx >> 4, cc = idx & 15;
      Winp[idx] = W_in_s1[(size_t)k * 512 + n0 + cc];
    }
  }

  // biases / global-seg pointer in registers
  f4 bias;
  f4 beff2 = {0.f, 0.f, 0.f, 0.f};
  const float* Wg;
  if (region == 0) {
    bias = *(const f4*)(b_pmd_m1 + n);
    Wg = W_rec_m1;
  } else if (region == 1) {
    bias  = *(const f4*)(b_m1_pmd + n);
    bias += *(const f4*)(b_s1_pmd + n);
    bias += *(const f4*)(b_fb_pmd + n);
    beff2 = b_out_m1[0] * *(const f4*)(W_fb_pmd + n)
          + b_out_m1[1] * *(const f4*)(W_fb_pmd + 512 + n);
    Wg = W_rec_pmd;
  } else {
    bias = *(const f4*)(b_in_s1 + n);
    Wg = W_rec_s1;
  }
  __syncthreads();

  float* xp   = ws + region * 32768 + bb * 512 + n;   // thread-owned x
  float* prow = partial + bb * 512 + n;

  for (int t = 1; t < TSTEPS; ++t) {
    const float* rm1p  = dout + OFF_RM1 + (size_t)(t - 1) * 32768;
    const float* rpmdp = rm1p + RSTRIDE;
    const float* rs1p  = rpmdp + RSTRIDE;
    f4 pre;

    if (region == 2) {
      // --- s1: phase 1: partial for pmd (LDS seg), publish early ---
      const float* ra = rs1p + bb * 512;
      f4 accP = {0.f, 0.f, 0.f, 0.f};
      #pragma unroll 2
      for (int k0 = 0; k0 < 512; k0 += 4) {
        f4 r = *(const f4*)(ra + k0);
        const float* wl = &Wl[k0 * 16 + nq * 4];
        f4 a0 = *(const f4*)(wl);
        f4 a1 = *(const f4*)(wl + 16);
        f4 a2 = *(const f4*)(wl + 32);
        f4 a3 = *(const f4*)(wl + 48);
        accP += r.x * a0; accP += r.y * a1; accP += r.z * a2; accP += r.w * a3;
      }
      publish4(prow, accP);
      asm volatile("s_waitcnt vmcnt(0)" ::: "memory");
      __syncthreads();
      if (tid == 0)
        __hip_atomic_fetch_add(&flags[c], 1, __ATOMIC_RELAXED, __HIP_MEMORY_SCOPE_AGENT);
      // --- phase 2: own recurrence (global seg) + input ---
      f4 accX = {0.f, 0.f, 0.f, 0.f};
      const float* wg = Wg + n;
      #pragma unroll 2
      for (int k0 = 0; k0 < 512; k0 += 4) {
        f4 r  = *(const f4*)(ra + k0);
        f4 g0 = *(const f4*)(wg);
        f4 g1 = *(const f4*)(wg + 512);
        f4 g2 = *(const f4*)(wg + 1024);
        f4 g3 = *(const f4*)(wg + 1536);
        wg += 2048;
        accX += r.x * g0; accX += r.y * g1; accX += r.z * g2; accX += r.w * g3;
      }
      const float* u = stim + (size_t)t * 640 + bb * 10;
      f4 accI = bias;
      #pragma unroll
      for (int j = 0; j < 10; ++j)
        accI += u[j] * *(const f4*)(&Winp[j * 16 + nq * 4]);
      pre = accX + accI;
    } else {
      // --- m1 / pmd: fused dual-segment loop (LDS pipe + VMEM pipe) ---
      const float* ra = (region == 0 ? rpmdp : rm1p)  + bb * 512;  // LDS-seg src
      const float* rb = (region == 0 ? rm1p  : rpmdp) + bb * 512;  // GLB-seg src
      f4 accA = {0.f, 0.f, 0.f, 0.f};
      f4 accB = {0.f, 0.f, 0.f, 0.f};
      const float* wg = Wg + n;
      #pragma unroll 2
      for (int k0 = 0; k0 < 512; k0 += 4) {
        f4 r1 = *(const f4*)(ra + k0);
        f4 r2 = *(const f4*)(rb + k0);
        const float* wl = &Wl[k0 * 16 + nq * 4];
        f4 a0 = *(const f4*)(wl);
        f4 a1 = *(const f4*)(wl + 16);
        f4 a2 = *(const f4*)(wl + 32);
        f4 a3 = *(const f4*)(wl + 48);
        f4 g0 = *(const f4*)(wg);
        f4 g1 = *(const f4*)(wg + 512);
        f4 g2 = *(const f4*)(wg + 1024);
        f4 g3 = *(const f4*)(wg + 1536);
        wg += 2048;
        accA += r1.x * a0; accA += r1.y * a1; accA += r1.z * a2; accA += r1.w * a3;
        accB += r2.x * g0; accB += r2.y * g1; accB += r2.z * g2; accB += r2.w * g3;
      }
      if (region == 0) {
        pre = accA + accB + bias;
      } else {
        // wait for s1's partial (tid0 polls once for the block; 1 fabric
        // load per poll instead of 256 per-lane atomics)
        if (tid == 0) {
          while (__hip_atomic_load(&flags[c], __ATOMIC_RELAXED, __HIP_MEMORY_SCOPE_AGENT) < t)
            __builtin_amdgcn_s_sleep(1);
        }
        asm volatile("" ::: "memory");
        __syncthreads();
        pre = accA + accB + bias + fetch4(prow);
        if (t >= 2) pre += beff2;
      }
    }

    // ---- leaky update + tanh; x thread-owned; rate published coherent ----
    f4 xv = *(const f4*)xp;
    xv = 0.8f * xv + 0.2f * pre;
    *(f4*)xp = xv;
    f4 rv = {tanhf(xv.x), tanhf(xv.y), tanhf(xv.z), tanhf(xv.w)};
    float* rh = dout + OFF_RM1 + (size_t)region * RSTRIDE
              + (size_t)t * 32768 + bb * 512 + n;
    publish4(rh, rv);
    asm volatile("s_waitcnt vmcnt(0)" ::: "memory");

    gridbar(barctr, t * NBLK);
  }
}

extern "C" void kernel_launch(void* const* d_in, const int* in_sizes, int n_in,
                              void* d_out, int out_size, void* d_ws, size_t ws_size,
                              hipStream_t stream) {
  const float* stim      = (const float*)d_in[0];
  const float* W_rec_m1  = (const float*)d_in[1];
  const float* W_rec_pmd = (const float*)d_in[2];
  const float* W_rec_s1  = (const float*)d_in[3];
  const float* W_pmd_m1  = (const float*)d_in[4];
  const float* b_pmd_m1  = (const float*)d_in[5];
  const float* W_m1_pmd  = (const float*)d_in[6];
  const float* b_m1_pmd  = (const float*)d_in[7];
  const float* W_s1_pmd  = (const float*)d_in[8];
  const float* b_s1_pmd  = (const float*)d_in[9];
  const float* W_in_s1   = (const float*)d_in[10];
  const float* b_in_s1   = (const float*)d_in[11];
  const float* W_out_m1  = (const float*)d_in[12];
  const float* b_out_m1  = (const float*)d_in[13];
  const float* W_fb_pmd  = (const float*)d_in[14];
  const float* b_fb_pmd  = (const float*)d_in[15];

  float* ws   = (float*)d_ws;
  float* dout = (float*)d_out;

  hipLaunchKernelGGL(rnn_init, dim3(512), dim3(256), 0, stream, ws, dout);

  void* args[] = {
    (void*)&stim,
    (void*)&W_rec_m1, (void*)&W_rec_pmd, (void*)&W_rec_s1,
    (void*)&W_pmd_m1, (void*)&b_pmd_m1,
    (void*)&W_m1_pmd, (void*)&b_m1_pmd,
    (void*)&W_s1_pmd, (void*)&b_s1_pmd,
    (void*)&W_in_s1,  (void*)&b_in_s1,
    (void*)&W_out_m1, (void*)&b_out_m1,
    (void*)&W_fb_pmd, (void*)&b_fb_pmd,
    (void*)&ws, (void*)&dout
  };
  hipLaunchCooperativeKernel((const void*)rnn_persist, dim3(NBLK), dim3(256),
                             args, 0, stream);
}

// Round 4
// 9650.736 us; speedup vs baseline: 2.2412x; 1.0917x over previous
//
#include <hip/hip_runtime.h>

// Problem constants
#define TSTEPS 300
// d_out float-element offsets: [outs 300*64*2 | r_m1 | r_pmd | r_s1]
#define OFF_RM1  38400
#define RSTRIDE  9830400    // 300*64*512 per rate region

// Geometry: 8 domains (dom = blk&7, XCD-pinned heuristic) x 8 batch rows.
// Per domain: 24 compute blocks (3 regions x 8 colblocks of 64 cols) +
// 1 passive out-writer = 25. 200 blocks x 512 threads, cooperative.
#define DOMS 8
#define DROWS 8
#define CPD 24              // compute blocks per domain (barrier population)
#define NBLK 200
#define THREADS 512
#define PAD 520             // LDS row pitch (floats) -> conflict-free dot reads
#define PSTR (DROWS*PAD)    // panel stride (floats)

typedef float f4 __attribute__((ext_vector_type(4)));
typedef unsigned long long u64;

// ws: int area only (barrier counters, 64B-strided per domain)
#define WS_INTS 128

// rate publish: two 8B relaxed agent-scope atomic stores (sc1 write-through
// to the coherence point; no fences/wbl2 needed) — proven pattern (round 2).
__device__ __forceinline__ void publish16(float* p, f4 v) {
  union { f4 f; u64 q[2]; } u; u.f = v;
  __hip_atomic_store((u64*)p,       u.q[0], __ATOMIC_RELAXED, __HIP_MEMORY_SCOPE_AGENT);
  __hip_atomic_store(((u64*)p) + 1, u.q[1], __ATOMIC_RELAXED, __HIP_MEMORY_SCOPE_AGENT);
}

// outs row-dot: identical algorithm at both call sites (pmd feedback and the
// lagging writer) -> bitwise-identical results. rrow = 512 floats.
__device__ __forceinline__ void out_dot(const float* rrow, const float* W_out,
                                        float& o0, float& o1) {
  const int lane = threadIdx.x & 63;
  f4 ra = *(const f4*)(rrow + lane * 8);
  f4 rb = *(const f4*)(rrow + lane * 8 + 4);
  f4 w0 = *(const f4*)(W_out + lane * 16);
  f4 w1 = *(const f4*)(W_out + lane * 16 + 4);
  f4 w2 = *(const f4*)(W_out + lane * 16 + 8);
  f4 w3 = *(const f4*)(W_out + lane * 16 + 12);
  o0 = ra.x*w0.x + ra.y*w0.z + ra.z*w1.x + ra.w*w1.z
     + rb.x*w2.x + rb.y*w2.z + rb.z*w3.x + rb.w*w3.z;
  o1 = ra.x*w0.y + ra.y*w0.w + ra.z*w1.y + ra.w*w1.w
     + rb.x*w2.y + rb.y*w2.w + rb.z*w3.y + rb.w*w3.w;
  #pragma unroll
  for (int m = 1; m < 64; m <<= 1) {
    o0 += __shfl_xor(o0, m, 64);
    o1 += __shfl_xor(o1, m, 64);
  }
}

// ---------------------------------------------------------------------------
__global__ __launch_bounds__(256) void rnn_init(float* ws, float* dout) {
  int gid = blockIdx.x * blockDim.x + threadIdx.x;
  int stride = gridDim.x * blockDim.x;
  int* wi = (int*)ws;
  for (int i = gid; i < WS_INTS; i += stride) wi[i] = 0;
  for (int i = gid; i < 128; i += stride) dout[i] = 0.f;
  for (int i = gid; i < 3 * 32768; i += stride) {
    int rr = i >> 15, j = i & 32767;
    dout[OFF_RM1 + (size_t)rr * RSTRIDE + j] = 0.f;
  }
}

// ---------------------------------------------------------------------------
__global__ __launch_bounds__(THREADS, 1) void rnn_persist(
    const float* __restrict__ stim,
    const float* __restrict__ W_rec_m1, const float* __restrict__ W_rec_pmd,
    const float* __restrict__ W_rec_s1,
    const float* __restrict__ W_pmd_m1, const float* __restrict__ b_pmd_m1,
    const float* __restrict__ W_m1_pmd, const float* __restrict__ b_m1_pmd,
    const float* __restrict__ W_s1_pmd, const float* __restrict__ b_s1_pmd,
    const float* __restrict__ W_in_s1,  const float* __restrict__ b_in_s1,
    const float* __restrict__ W_out_m1, const float* __restrict__ b_out_m1,
    const float* __restrict__ W_fb_pmd, const float* __restrict__ b_fb_pmd,
    float* __restrict__ ws, float* __restrict__ dout)
{
  __shared__ float panel[3 * PSTR];   // up to 3 rate panels [seg][8][PAD]
  __shared__ f4    scr[3 * 128];      // K-split partials from tasks 1..3
  __shared__ float o_lds[16];         // pmd: outs[t-1] per row (o0,o1)

  const int blk = blockIdx.x;
  const int tid = threadIdx.x;
  const int dom = blk & 7;            // XCD-pinning heuristic (speed only)
  const int sub = blk >> 3;           // 0..24 within domain
  int* ctr = (int*)ws + dom * 16;     // per-domain barrier counter

  const float* rates0 = dout + OFF_RM1;            // r_m1 plane
  const int rowbase = dom * DROWS;

  // ================= passive lagging out-writer =================
  if (sub == 24) {
    const int wave = tid >> 6;
    const int lane = tid & 63;
    for (int t = 1; t < TSTEPS; ++t) {
      if (tid == 0) {
        while (__hip_atomic_load(ctr, __ATOMIC_RELAXED, __HIP_MEMORY_SCOPE_AGENT) < CPD * t)
          __builtin_amdgcn_s_sleep(2);
      }
      __syncthreads();
      // outs[t] = r_m1[t] @ W_out + b_out, one row per wave
      const int row = rowbase + wave;
      float o0, o1;
      out_dot(rates0 + (size_t)t * 32768 + row * 512, W_out_m1, o0, o1);
      if (lane == 0) {
        dout[(size_t)t * 128 + row * 2]     = o0 + b_out_m1[0];
        dout[(size_t)t * 128 + row * 2 + 1] = o1 + b_out_m1[1];
      }
      __syncthreads();
    }
    return;
  }

  // ================= compute blocks =================
  const int region = sub >> 3;        // 0=m1, 1=pmd, 2=s1
  const int c    = sub & 7;           // colblock (64 cols)
  const int task = tid >> 7;          // 4 K-split tasks x 128 threads
  const int s    = tid & 127;         // slot: 8 rows x 16 col-quads
  const int bb   = s >> 4;
  const int nq   = s & 15;
  const int n    = c * 64 + nq * 4;
  const int row  = rowbase + bb;

  // K-segment tables (wave-uniform selects, no runtime-indexed arrays)
  const float *WA, *WB = nullptr, *WC = nullptr;
  int nseg, KQ;
  if (region == 0)      { WA = W_rec_m1;  WB = W_pmd_m1;                  nseg = 2; KQ = 256; }
  else if (region == 1) { WA = W_rec_pmd; WB = W_m1_pmd; WC = W_s1_pmd;   nseg = 3; KQ = 384; }
  else                  { WA = W_rec_s1;                                  nseg = 1; KQ = 128; }

  // biases / feedback vectors (combiner threads use these)
  f4 bias, fb0 = {0,0,0,0}, fb1 = {0,0,0,0};
  if (region == 0) bias = *(const f4*)(b_pmd_m1 + n);
  else if (region == 1) {
    bias  = *(const f4*)(b_m1_pmd + n);
    bias += *(const f4*)(b_s1_pmd + n);
    bias += *(const f4*)(b_fb_pmd + n);
    fb0 = *(const f4*)(W_fb_pmd + n);
    fb1 = *(const f4*)(W_fb_pmd + 512 + n);
  } else bias = *(const f4*)(b_in_s1 + n);

  const int nseg2 = nseg * 2;         // f4 stage-loads per thread
  f4 xv = {0.f, 0.f, 0.f, 0.f};       // x-state lives in registers

  for (int t = 1; t < TSTEPS; ++t) {
    // panel sources (rates at t-1, rows of this domain)
    const float* rb_ = dout + OFF_RM1 + (size_t)(t - 1) * 32768 + rowbase * 512;
    const float *src0, *src1 = nullptr, *src2 = nullptr;
    if (region == 0)      { src0 = rb_;                    src1 = rb_ + RSTRIDE; }
    else if (region == 1) { src0 = rb_ + RSTRIDE;          src1 = rb_;
                            src2 = rb_ + 2 * (size_t)RSTRIDE; }
    else                  { src0 = rb_ + 2 * (size_t)RSTRIDE; }

    // ---- burst-stage panels: issue all loads, then all LDS writes ----
    {
      f4 tmp[6];
      #pragma unroll
      for (int i = 0; i < 6; ++i) {
        if (i < nseg2) {
          int j = tid + i * 512;          // f4 index over nseg*1024
          int p = j >> 10, idx = j & 1023;
          const float* sp = (p == 0) ? src0 : (p == 1) ? src1 : src2;
          tmp[i] = *(const f4*)(sp + (idx >> 7) * 512 + (idx & 127) * 4);
        }
      }
      #pragma unroll
      for (int i = 0; i < 6; ++i) {
        if (i < nseg2) {
          int j = tid + i * 512;
          int p = j >> 10, idx = j & 1023;
          *(f4*)(panel + p * PSTR + (idx >> 7) * PAD + (idx & 127) * 4) = tmp[i];
        }
      }
    }
    __syncthreads();

    // ---- K-split dot: task covers K' in [task*KQ, (task+1)*KQ) ----
    f4 acc = {0.f, 0.f, 0.f, 0.f};
    {
      int K = task * KQ, Khi = K + KQ;
      while (K < Khi) {
        int seg  = K >> 9;
        int kend = (seg + 1) << 9; if (kend > Khi) kend = Khi;
        const float* wg  = ((seg == 0) ? WA : (seg == 1) ? WB : WC)
                         + (size_t)(K & 511) * 512 + n;
        const float* pan = panel + seg * PSTR + bb * PAD + (K & 511);
        #pragma unroll 2
        for (int k = K; k < kend; k += 4) {
          f4 r  = *(const f4*)pan; pan += 4;
          f4 g0 = *(const f4*)(wg);
          f4 g1 = *(const f4*)(wg + 512);
          f4 g2 = *(const f4*)(wg + 1024);
          f4 g3 = *(const f4*)(wg + 1536);
          wg += 2048;
          acc += r.x * g0; acc += r.y * g1; acc += r.z * g2; acc += r.w * g3;
        }
        K = kend;
      }
    }

    // ---- pmd: local outs[t-1] from staged rm1 panel (waves = rows) ----
    if (region == 1) {
      const int wave = tid >> 6;
      float o0, o1;
      out_dot(panel + PSTR + wave * PAD, W_out_m1, o0, o1);
      if ((tid & 63) == 0) {
        o_lds[wave * 2]     = o0 + b_out_m1[0];
        o_lds[wave * 2 + 1] = o1 + b_out_m1[1];
      }
    }

    if (task > 0) scr[(task - 1) * 128 + s] = acc;
    __syncthreads();

    // ---- combine + leaky update + tanh + publish (tasks-0 threads) ----
    if (task == 0) {
      f4 pre = acc + scr[s] + scr[128 + s] + scr[256 + s] + bias;
      if (region == 1) {
        if (t >= 2) {
          float o0 = o_lds[bb * 2], o1 = o_lds[bb * 2 + 1];
          pre += o0 * fb0;
          pre += o1 * fb1;
        }
      } else if (region == 2) {
        const float* u = stim + (size_t)t * 640 + row * 10;
        #pragma unroll
        for (int j = 0; j < 10; ++j)
          pre += u[j] * *(const f4*)(W_in_s1 + j * 512 + n);
      }
      xv = 0.8f * xv + 0.2f * pre;
      f4 rv = {tanhf(xv.x), tanhf(xv.y), tanhf(xv.z), tanhf(xv.w)};
      publish16(dout + OFF_RM1 + (size_t)region * RSTRIDE + (size_t)t * 32768
                + row * 512 + n, rv);
    }

    // ---- domain barrier (24 compute blocks; monotonic counter) ----
    __syncthreads();   // drains the publish stores (vmcnt 0 before s_barrier)
    if (tid == 0) {
      __hip_atomic_fetch_add(ctr, 1, __ATOMIC_RELAXED, __HIP_MEMORY_SCOPE_AGENT);
      if (t < TSTEPS - 1) {
        while (__hip_atomic_load(ctr, __ATOMIC_RELAXED, __HIP_MEMORY_SCOPE_AGENT) < CPD * t)
          __builtin_amdgcn_s_sleep(1);
      }
    }
    __syncthreads();
  }
}

extern "C" void kernel_launch(void* const* d_in, const int* in_sizes, int n_in,
                              void* d_out, int out_size, void* d_ws, size_t ws_size,
                              hipStream_t stream) {
  const float* stim      = (const float*)d_in[0];
  const float* W_rec_m1  = (const float*)d_in[1];
  const float* W_rec_pmd = (const float*)d_in[2];
  const float* W_rec_s1  = (const float*)d_in[3];
  const float* W_pmd_m1  = (const float*)d_in[4];
  const float* b_pmd_m1  = (const float*)d_in[5];
  const float* W_m1_pmd  = (const float*)d_in[6];
  const float* b_m1_pmd  = (const float*)d_in[7];
  const float* W_s1_pmd  = (const float*)d_in[8];
  const float* b_s1_pmd  = (const float*)d_in[9];
  const float* W_in_s1   = (const float*)d_in[10];
  const float* b_in_s1   = (const float*)d_in[11];
  const float* W_out_m1  = (const float*)d_in[12];
  const float* b_out_m1  = (const float*)d_in[13];
  const float* W_fb_pmd  = (const float*)d_in[14];
  const float* b_fb_pmd  = (const float*)d_in[15];

  float* ws   = (float*)d_ws;
  float* dout = (float*)d_out;

  hipLaunchKernelGGL(rnn_init, dim3(256), dim3(256), 0, stream, ws, dout);

  void* args[] = {
    (void*)&stim,
    (void*)&W_rec_m1, (void*)&W_rec_pmd, (void*)&W_rec_s1,
    (void*)&W_pmd_m1, (void*)&b_pmd_m1,
    (void*)&W_m1_pmd, (void*)&b_m1_pmd,
    (void*)&W_s1_pmd, (void*)&b_s1_pmd,
    (void*)&W_in_s1,  (void*)&b_in_s1,
    (void*)&W_out_m1, (void*)&b_out_m1,
    (void*)&W_fb_pmd, (void*)&b_fb_pmd,
    (void*)&ws, (void*)&dout
  };
  hipLaunchCooperativeKernel((const void*)rnn_persist, dim3(NBLK), dim3(THREADS),
                             args, 0, stream);
}

// Round 5
// 9601.883 us; speedup vs baseline: 2.2526x; 1.0051x over previous
//
#include <hip/hip_runtime.h>

// Problem constants
#define TSTEPS 300
// d_out float-element offsets: [outs 300*64*2 | r_m1 | r_pmd | r_s1]
#define OFF_RM1  38400
#define RSTRIDE  9830400    // 300*64*512 per rate region

// Geometry: 4 domains x 16 batch rows. Block = (dom, src-region, colblock).
// src block stages ONE rate panel (16x512) and computes BOTH matrices fed by
// that source: own-recurrent (keeps) + message (exports partial).
// XCD pinning heuristic: XCD = blk&7 = src*2 + (dom&1) -> 16 blocks/XCD
// sharing the same 2 MB weight pair => L2-resident.
#define DOMS 4
#define DROWS 16
#define CPD 24              // compute blocks per domain (barrier population)
#define NBLK 128            // grid (28 blocks decode to no-role and exit)
#define THREADS 512
#define PAD 516             // LDS panel row pitch (floats): conflict-free

// ws float layout:
//   [0 .. 98303]  partials P[dom][edge][c][16][64]  (edge = exporting src)
//   [98304 .. ]   ints: flags[(dom*3+edge)*8+c] stride 16; barctr[dom] at 1536+dom*16
#define WS_INT_F 98304
#define WS_INTS  1600
#define WS_TOTAL 99904

typedef float f4 __attribute__((ext_vector_type(4)));
typedef unsigned long long u64;

// sc1 write-through publish (agent-visible, no fences) — round-2/4 proven
__device__ __forceinline__ void publish16(float* p, f4 v) {
  union { f4 f; u64 q[2]; } u; u.f = v;
  __hip_atomic_store((u64*)p,       u.q[0], __ATOMIC_RELAXED, __HIP_MEMORY_SCOPE_AGENT);
  __hip_atomic_store(((u64*)p) + 1, u.q[1], __ATOMIC_RELAXED, __HIP_MEMORY_SCOPE_AGENT);
}
// coherent read of reused buffers (bypasses stale local L2) — round-2 proven
__device__ __forceinline__ f4 fetch4(const float* p) {
  f4 v;
  v.x = __hip_atomic_load(p + 0, __ATOMIC_RELAXED, __HIP_MEMORY_SCOPE_AGENT);
  v.y = __hip_atomic_load(p + 1, __ATOMIC_RELAXED, __HIP_MEMORY_SCOPE_AGENT);
  v.z = __hip_atomic_load(p + 2, __ATOMIC_RELAXED, __HIP_MEMORY_SCOPE_AGENT);
  v.w = __hip_atomic_load(p + 3, __ATOMIC_RELAXED, __HIP_MEMORY_SCOPE_AGENT);
  return v;
}

// full-row out dot (one wave wide), global-pointer version for the writer
__device__ __forceinline__ void out_dot(const float* rrow, const float* W_out,
                                        float& o0, float& o1) {
  const int lane = threadIdx.x & 63;
  f4 ra = *(const f4*)(rrow + lane * 8);
  f4 rb = *(const f4*)(rrow + lane * 8 + 4);
  f4 w0 = *(const f4*)(W_out + lane * 16);
  f4 w1 = *(const f4*)(W_out + lane * 16 + 4);
  f4 w2 = *(const f4*)(W_out + lane * 16 + 8);
  f4 w3 = *(const f4*)(W_out + lane * 16 + 12);
  o0 = ra.x*w0.x + ra.y*w0.z + ra.z*w1.x + ra.w*w1.z
     + rb.x*w2.x + rb.y*w2.z + rb.z*w3.x + rb.w*w3.z;
  o1 = ra.x*w0.y + ra.y*w0.w + ra.z*w1.y + ra.w*w1.w
     + rb.x*w2.y + rb.y*w2.w + rb.z*w3.y + rb.w*w3.w;
  #pragma unroll
  for (int m = 1; m < 64; m <<= 1) {
    o0 += __shfl_xor(o0, m, 64);
    o1 += __shfl_xor(o1, m, 64);
  }
}

// ---------------------------------------------------------------------------
__global__ __launch_bounds__(256) void rnn_init(float* ws, float* dout) {
  int gid = blockIdx.x * blockDim.x + threadIdx.x;
  int stride = gridDim.x * blockDim.x;
  int* wi = (int*)(ws + WS_INT_F);
  for (int i = gid; i < WS_INTS; i += stride) wi[i] = 0;
  for (int i = gid; i < 128; i += stride) dout[i] = 0.f;
  for (int i = gid; i < 3 * 32768; i += stride) {
    int rr = i >> 15, j = i & 32767;
    dout[OFF_RM1 + (size_t)rr * RSTRIDE + j] = 0.f;
  }
}

// ---------------------------------------------------------------------------
__global__ __launch_bounds__(THREADS, 1) void rnn_persist(
    const float* __restrict__ stim,
    const float* __restrict__ W_rec_m1, const float* __restrict__ W_rec_pmd,
    const float* __restrict__ W_rec_s1,
    const float* __restrict__ W_pmd_m1, const float* __restrict__ b_pmd_m1,
    const float* __restrict__ W_m1_pmd, const float* __restrict__ b_m1_pmd,
    const float* __restrict__ W_s1_pmd, const float* __restrict__ b_s1_pmd,
    const float* __restrict__ W_in_s1,  const float* __restrict__ b_in_s1,
    const float* __restrict__ W_out_m1, const float* __restrict__ b_out_m1,
    const float* __restrict__ W_fb_pmd, const float* __restrict__ b_fb_pmd,
    float* __restrict__ ws, float* __restrict__ dout)
{
  __shared__ float panel[DROWS * PAD];   // one source-rate panel [16][PAD]
  __shared__ f4    scr[256];             // K-task-1 partials
  __shared__ float o_lds[32];            // outs[t-1] per row (o0,o1), src0 only

  const int blk = blockIdx.x;
  const int tid = threadIdx.x;
  const int x = blk & 7;                 // XCD slot (heuristic)
  const int jj = blk >> 3;

  int* ibase = (int*)(ws + WS_INT_F);

  // ================= passive lagging out-writer (XCD 6) =================
  if (x == 6) {
    if (jj >= DOMS) return;
    const int dom = jj;
    const int rowbase = dom * DROWS;
    int* ctr = ibase + 1536 + dom * 16;
    const float* rates0 = dout + OFF_RM1;
    const int wave = tid >> 6, lane = tid & 63;
    for (int t = 1; t < TSTEPS; ++t) {
      if (tid == 0) {
        while (__hip_atomic_load(ctr, __ATOMIC_RELAXED, __HIP_MEMORY_SCOPE_AGENT) < CPD * t)
          __builtin_amdgcn_s_sleep(2);
      }
      __syncthreads();
      #pragma unroll
      for (int h = 0; h < 2; ++h) {
        int rr = rowbase + wave + h * 8;
        float o0, o1;
        out_dot(rates0 + (size_t)t * 32768 + rr * 512, W_out_m1, o0, o1);
        if (lane == 0) {
          dout[(size_t)t * 128 + rr * 2]     = o0 + b_out_m1[0];
          dout[(size_t)t * 128 + rr * 2 + 1] = o1 + b_out_m1[1];
        }
      }
      __syncthreads();
    }
    return;
  }
  if (x == 7 || jj >= 16) return;

  // ================= compute blocks =================
  const int src = x >> 1;                  // source region 0=m1,1=pmd,2=s1
  const int dom = (x & 1) + 2 * (jj >> 3); // 0..3
  const int c   = jj & 7;                  // colblock (64 cols)
  const int rowbase = dom * DROWS;

  const int task = tid >> 8;               // 2 K-tasks x 256 threads
  const int s    = tid & 255;              // 16 rows x 16 col-quads
  const int bb   = s >> 4;
  const int nq   = s & 15;
  const int n    = c * 64 + nq * 4;        // global col 0..511
  const int row  = rowbase + bb;

  // matrices fed by this source: own (recurrent, kept) + export (message)
  const float *Wown, *Wexp;
  if (src == 0)      { Wown = W_rec_m1;  Wexp = W_m1_pmd; }
  else if (src == 1) { Wown = W_rec_pmd; Wexp = W_pmd_m1; }
  else               { Wown = W_rec_s1;  Wexp = W_s1_pmd; }

  // own-target bias (src == own target region)
  f4 bias, fbv0 = {0,0,0,0}, fbv1 = {0,0,0,0};
  if (src == 0) {
    bias = *(const f4*)(b_pmd_m1 + n);
    fbv0 = *(const f4*)(W_fb_pmd + n);        // feedback folded into export
    fbv1 = *(const f4*)(W_fb_pmd + 512 + n);
  } else if (src == 1) {
    bias  = *(const f4*)(b_m1_pmd + n);
    bias += *(const f4*)(b_s1_pmd + n);
    bias += *(const f4*)(b_fb_pmd + n);
  } else bias = *(const f4*)(b_in_s1 + n);

  // partial scratch + flags
  float* Pexp = ws + ((size_t)(dom * 3 + src) * 8 + c) * 1024;
  float* Prd0 = ws + ((size_t)(dom * 3 + ((src == 0) ? 1 : 0)) * 8 + c) * 1024;
  float* Prd2 = ws + ((size_t)(dom * 3 + 2) * 8 + c) * 1024;
  int* myflag = ibase + ((dom * 3 + src) * 8 + c) * 16;
  int* rdf0   = ibase + ((dom * 3 + ((src == 0) ? 1 : 0)) * 8 + c) * 16;
  int* rdf2   = ibase + ((dom * 3 + 2) * 8 + c) * 16;
  int* ctr    = ibase + 1536 + dom * 16;
  const int off = bb * 64 + nq * 4;

  f4 xv = {0.f, 0.f, 0.f, 0.f};            // x-state in registers (task0)

  for (int t = 1; t < TSTEPS; ++t) {
    // ---- burst-stage the source panel (16 rows x 512) ----
    {
      const float* srcp = dout + OFF_RM1 + (size_t)src * RSTRIDE
                        + (size_t)(t - 1) * 32768 + rowbase * 512;
      f4 tmp[4];
      #pragma unroll
      for (int i = 0; i < 4; ++i) {
        int j2 = tid + i * 512;
        tmp[i] = *(const f4*)(srcp + (j2 >> 7) * 512 + (j2 & 127) * 4);
      }
      #pragma unroll
      for (int i = 0; i < 4; ++i) {
        int j2 = tid + i * 512;
        *(f4*)(panel + (j2 >> 7) * PAD + (j2 & 127) * 4) = tmp[i];
      }
    }
    __syncthreads();

    // ---- src0: outs[t-1] from the staged rm1 panel (for feedback fold) ----
    if (src == 0 && t >= 2) {
      int rr = tid >> 5, kc = tid & 31;
      const float* pr = panel + rr * PAD;
      float o0 = 0.f, o1 = 0.f;
      #pragma unroll
      for (int i = 0; i < 4; ++i) {
        int k = kc * 4 + i * 128;
        f4 r  = *(const f4*)(pr + k);
        f4 wa = *(const f4*)(W_out_m1 + k * 2);
        f4 wb = *(const f4*)(W_out_m1 + k * 2 + 4);
        o0 += r.x*wa.x + r.y*wa.z + r.z*wb.x + r.w*wb.z;
        o1 += r.x*wa.y + r.y*wa.w + r.z*wb.y + r.w*wb.w;
      }
      #pragma unroll
      for (int m = 1; m < 32; m <<= 1) {
        o0 += __shfl_xor(o0, m, 64);
        o1 += __shfl_xor(o1, m, 64);
      }
      if ((tid & 31) == 0) {
        o_lds[rr * 2]     = o0 + b_out_m1[0];
        o_lds[rr * 2 + 1] = o1 + b_out_m1[1];
      }
    }

    // ---- dot 1: export (message) matrix ----
    f4 acc;
    {
      const float* wg  = Wexp + (size_t)(task * 256) * 512 + n;
      const float* pan = panel + bb * PAD + task * 256;
      f4 a = {0.f, 0.f, 0.f, 0.f};
      #pragma unroll 2
      for (int kk = 0; kk < 256; kk += 4) {
        f4 r  = *(const f4*)(pan + kk);
        f4 g0 = *(const f4*)(wg);
        f4 g1 = *(const f4*)(wg + 512);
        f4 g2 = *(const f4*)(wg + 1024);
        f4 g3 = *(const f4*)(wg + 1536);
        wg += 2048;
        a += r.x * g0; a += r.y * g1; a += r.z * g2; a += r.w * g3;
      }
      acc = a;
    }
    if (task == 1) scr[s] = acc;
    __syncthreads();
    if (task == 0) {
      f4 pe = acc + scr[s];
      if (src == 0 && t >= 2) {
        pe += o_lds[bb * 2]     * fbv0;
        pe += o_lds[bb * 2 + 1] * fbv1;
      }
      publish16(Pexp + off, pe);
    }
    __syncthreads();   // drains publishes (vmcnt 0) before flag release
    if (tid == 0)
      __hip_atomic_fetch_add(myflag, 1, __ATOMIC_RELAXED, __HIP_MEMORY_SCOPE_AGENT);

    // ---- dot 2: own recurrent matrix ----
    {
      const float* wg  = Wown + (size_t)(task * 256) * 512 + n;
      const float* pan = panel + bb * PAD + task * 256;
      f4 a = {0.f, 0.f, 0.f, 0.f};
      #pragma unroll 2
      for (int kk = 0; kk < 256; kk += 4) {
        f4 r  = *(const f4*)(pan + kk);
        f4 g0 = *(const f4*)(wg);
        f4 g1 = *(const f4*)(wg + 512);
        f4 g2 = *(const f4*)(wg + 1024);
        f4 g3 = *(const f4*)(wg + 1536);
        wg += 2048;
        a += r.x * g0; a += r.y * g1; a += r.z * g2; a += r.w * g3;
      }
      acc = a;
    }
    if (task == 1) scr[s] = acc;
    if (tid == 0) {       // poll needed import flags while others sync
      if (src == 0) {
        while (__hip_atomic_load(rdf0, __ATOMIC_RELAXED, __HIP_MEMORY_SCOPE_AGENT) < t)
          __builtin_amdgcn_s_sleep(1);
      } else if (src == 1) {
        while (__hip_atomic_load(rdf0, __ATOMIC_RELAXED, __HIP_MEMORY_SCOPE_AGENT) < t)
          __builtin_amdgcn_s_sleep(1);
        while (__hip_atomic_load(rdf2, __ATOMIC_RELAXED, __HIP_MEMORY_SCOPE_AGENT) < t)
          __builtin_amdgcn_s_sleep(1);
      }
    }
    __syncthreads();

    // ---- combine + leaky update + tanh + publish rates (task 0) ----
    if (task == 0) {
      f4 pre = acc + scr[s] + bias;
      if (src == 0) {
        pre += fetch4(Prd0 + off);                 // pmd_m1 import
      } else if (src == 1) {
        pre += fetch4(Prd0 + off);                 // m1_pmd (+folded feedback)
        pre += fetch4(Prd2 + off);                 // s1_pmd
      } else {
        const float* u = stim + (size_t)t * 640 + row * 10;
        #pragma unroll
        for (int j = 0; j < 10; ++j)
          pre += u[j] * *(const f4*)(W_in_s1 + j * 512 + n);
      }
      xv = 0.8f * xv + 0.2f * pre;
      f4 rv = {tanhf(xv.x), tanhf(xv.y), tanhf(xv.z), tanhf(xv.w)};
      publish16(dout + OFF_RM1 + (size_t)src * RSTRIDE + (size_t)t * 32768
                + row * 512 + n, rv);
    }

    // ---- domain barrier (24 compute blocks; monotonic counter) ----
    __syncthreads();   // drains rate publishes before arrival
    if (tid == 0) {
      __hip_atomic_fetch_add(ctr, 1, __ATOMIC_RELAXED, __HIP_MEMORY_SCOPE_AGENT);
      if (t < TSTEPS - 1) {
        while (__hip_atomic_load(ctr, __ATOMIC_RELAXED, __HIP_MEMORY_SCOPE_AGENT) < CPD * t)
          __builtin_amdgcn_s_sleep(1);
      }
    }
    __syncthreads();
  }
}

extern "C" void kernel_launch(void* const* d_in, const int* in_sizes, int n_in,
                              void* d_out, int out_size, void* d_ws, size_t ws_size,
                              hipStream_t stream) {
  const float* stim      = (const float*)d_in[0];
  const float* W_rec_m1  = (const float*)d_in[1];
  const float* W_rec_pmd = (const float*)d_in[2];
  const float* W_rec_s1  = (const float*)d_in[3];
  const float* W_pmd_m1  = (const float*)d_in[4];
  const float* b_pmd_m1  = (const float*)d_in[5];
  const float* W_m1_pmd  = (const float*)d_in[6];
  const float* b_m1_pmd  = (const float*)d_in[7];
  const float* W_s1_pmd  = (const float*)d_in[8];
  const float* b_s1_pmd  = (const float*)d_in[9];
  const float* W_in_s1   = (const float*)d_in[10];
  const float* b_in_s1   = (const float*)d_in[11];
  const float* W_out_m1  = (const float*)d_in[12];
  const float* b_out_m1  = (const float*)d_in[13];
  const float* W_fb_pmd  = (const float*)d_in[14];
  const float* b_fb_pmd  = (const float*)d_in[15];

  float* ws   = (float*)d_ws;
  float* dout = (float*)d_out;

  hipLaunchKernelGGL(rnn_init, dim3(256), dim3(256), 0, stream, ws, dout);

  void* args[] = {
    (void*)&stim,
    (void*)&W_rec_m1, (void*)&W_rec_pmd, (void*)&W_rec_s1,
    (void*)&W_pmd_m1, (void*)&b_pmd_m1,
    (void*)&W_m1_pmd, (void*)&b_m1_pmd,
    (void*)&W_s1_pmd, (void*)&b_s1_pmd,
    (void*)&W_in_s1,  (void*)&b_in_s1,
    (void*)&W_out_m1, (void*)&b_out_m1,
    (void*)&W_fb_pmd, (void*)&b_fb_pmd,
    (void*)&ws, (void*)&dout
  };
  hipLaunchCooperativeKernel((const void*)rnn_persist, dim3(NBLK), dim3(THREADS),
                             args, 0, stream);
}